// Round 5
// baseline (1654.343 us; speedup 1.0000x reference)
//
#include <hip/hip_runtime.h>

#define TT 2048
#define SS 128
#define DMAXX 128
#define NBATCH 64

typedef float f2 __attribute__((ext_vector_type(2)));

__device__ __forceinline__ float fexp2(float x){ return __builtin_amdgcn_exp2f(x); }
__device__ __forceinline__ float flog2(float x){ return __builtin_amdgcn_logf(x); }
__device__ __forceinline__ float frcp (float x){ return __builtin_amdgcn_rcpf(x); }

__device__ __forceinline__ f2 pk_mul(f2 a, f2 b){
    f2 d; asm("v_pk_mul_f32 %0, %1, %2" : "=v"(d) : "v"(a), "v"(b)); return d;
}
__device__ __forceinline__ f2 pk_fma(f2 a, f2 b, f2 c){
    f2 d; asm("v_pk_fma_f32 %0, %1, %2, %3" : "=v"(d) : "v"(a), "v"(b), "v"(c)); return d;
}

template<int CTRL>
__device__ __forceinline__ float dppf(float x) {
    int i = __float_as_int(x);
    return __int_as_float(__builtin_amdgcn_update_dpp(i, i, CTRL, 0xF, 0xF, false));
}
template<int S>
__device__ __forceinline__ f2 rotr(f2 u) {   // row_ror:S on both halves
    f2 v; v.x = dppf<0x120 + S>(u.x); v.y = dppf<0x120 + S>(u.y); return v;
}
__device__ __forceinline__ float bperm(int addr, float v){
    return __int_as_float(__builtin_amdgcn_ds_bpermute(addr, __float_as_int(v)));
}

constexpr float LOG2E = 1.4426950408889634f;
constexpr float LN2   = 0.6931471805599453f;

struct State {
    f2 rp[16];    // ring (register-renamed): reg rho=31-PHI receives the new slot
    f2 eAr[16];   // rotation-matched eA pairs (direction resolved at runtime)
    f2 eDe[16];   // (eD[2k], eD[2k+1])
    f2 eDo[16];   // (eD[2k+1], eD[(2k+2)&31])
    float eD0;    // exp(D[j][0]) — lag-1 weight for the freshly inserted slot
    float pf[4];  // logB prefetch (distance 4)
    float C;
    float e_pi;
};

struct Ctx {
    const f2*    up0; const f2*    up1;   // distributed U_prev read: lane l -> pair l
    const float* wm0; const float* wm1;   // wmax read: lane reads wmax[pb][l&7]
    float*       w0p; float*       w1p;   // merged write ptr (lanes 0..16)
    int ax16, ax32, acar;                 // bpermute byte addrs
    bool wlt16, wact;                     // lane<16 (writes U), lane<=16 (write active)
    int  row0;                            // q == 0
    const float* lb;
};

template<int PHI>
__device__ __forceinline__ void hsmm_step(State& st, const Ctx& c, int tb)
{
    constexpr int rho = 31 - PHI;
    constexpr int pb  = (PHI + 1) & 1;
    constexpr int wb  = PHI & 1;
    const int t = tb + PHI;

    // ---- issue LDS ops first ----
    float wmv = (pb ? c.wm1 : c.wm0)[0];           // wmax[pb][l&7] (ptr pre-offset)
    f2 u = (pb ? c.up1 : c.up0)[0];                // U_prev pair l (ptr pre-offset)
    float rold;                                    // expiring slot, pre-scale
    if constexpr (rho & 1) rold = st.rp[rho >> 1].y; else rold = st.rp[rho >> 1].x;
    float car = bperm(c.acar, rold);               // row q gets row q-1's expiring slot

    // ---- normalizer m = max over 8 wave-maxes (direction-proof ror reduce) ----
    float m = wmv;
    m = fmaxf(m, dppf<0x121>(m));
    m = fmaxf(m, dppf<0x122>(m));
    m = fmaxf(m, dppf<0x124>(m));
    st.C += flog2(m) * LN2;
    float inv_m = frcp(m);

    // ---- emission multiplier; keep prefetch 4 ahead ----
    float xB = st.pf[PHI & 3];                     // logB[t]
    if (t + 4 < TT) st.pf[PHI & 3] = c.lb[(size_t)(t + 4) * SS];
    float g = fexp2(xB * LOG2E) * inv_m;

    // ---- trans: circulate U pairs around the row via DPP, FMA vs eAr ----
    f2 a0 = pk_mul(u, st.eAr[0]);
    f2 a1; a1.x = 0.f; a1.y = 0.f;
#define TROT(S) { f2 v = rotr<S>(u); if constexpr (S & 1) a1 = pk_fma(v, st.eAr[S], a1); \
                  else a0 = pk_fma(v, st.eAr[S], a0); }
    TROT(1) TROT(2) TROT(3) TROT(4) TROT(5) TROT(6) TROT(7)
    TROT(8) TROT(9) TROT(10) TROT(11) TROT(12) TROT(13) TROT(14) TROT(15)
#undef TROT
    f2 asum = a0 + a1;
    float s1 = asum.x + asum.y;                    // chunk-q partial for state j
    s1 += bperm(c.ax16, s1);
    s1 += bperm(c.ax32, s1);                       // full Etrans[j] at all lanes
    float tpv = s1;
    if constexpr (PHI == 0) { if (tb == 0) tpv = st.e_pi; }

    // ---- ring scale + insert (row0 inserts 0 during dur; patched after) ----
    float insg = (c.row0 ? 0.f : car) * g;
    f2 gg; gg.x = g; gg.y = g;
#pragma unroll
    for (int m2 = 0; m2 < 16; ++m2) st.rp[m2] = pk_mul(st.rp[m2], gg);
    if constexpr (rho & 1) st.rp[rho >> 1].y = insg;
    else                   st.rp[rho >> 1].x = insg;

    // ---- duration sum (R4's verified rotating eD banks) ----
    f2 qa; qa.x = 0.f; qa.y = 0.f;
    f2 qb; qb.x = 0.f; qb.y = 0.f;
#pragma unroll
    for (int m2 = 0; m2 < 16; ++m2) {
        f2 w;
        if constexpr (PHI & 1) w = st.eDe[(m2 + ((PHI + 1) >> 1)) & 15];
        else                   w = st.eDo[(m2 + (PHI >> 1)) & 15];
        if (m2 & 1) qb = pk_fma(st.rp[m2], w, qb);
        else        qa = pk_fma(st.rp[m2], w, qa);
    }
    f2 qs = qa + qb;
    float d1 = qs.x + qs.y;                        // chunk-q duration partial
    d1 += bperm(c.ax16, d1);
    d1 += bperm(c.ax32, d1);                       // sum over 4 rows (lags 2..128)

    float tpg = tpv * g;
    float U = fmaf(tpg, st.eD0, d1);               // + lag-1 slot contribution

    // patch row0's ring slot with the real inserted value
    if (c.row0) {
        if constexpr (rho & 1) st.rp[rho >> 1].y = tpg;
        else                   st.rp[rho >> 1].x = tpg;
    }

    // ---- wave max over the row's 16 states (direction-proof) ----
    float wm = U;
    wm = fmaxf(wm, dppf<0x121>(wm));
    wm = fmaxf(wm, dppf<0x122>(wm));
    wm = fmaxf(wm, dppf<0x124>(wm));
    wm = fmaxf(wm, dppf<0x128>(wm));

    // ---- merged write: lanes 0..15 -> ua[wb][j], lane 16 -> wmax[wb][wave] ----
    float data = c.wlt16 ? U : wm;
    if (c.wact) *(wb ? c.w1p : c.w0p) = data;

    asm volatile("s_waitcnt lgkmcnt(0)\n\ts_barrier" ::: "memory");
}

__launch_bounds__(512, 2)
__global__ void hsmm_fwd_kernel(const float* __restrict__ logB,
                                const float* __restrict__ pi,
                                const float* __restrict__ A,
                                const float* __restrict__ D,
                                float* __restrict__ out)
{
    const int b   = blockIdx.x;
    const int tid = threadIdx.x;
    const int l   = tid & 63;
    const int w   = tid >> 6;
    const int q   = l >> 4;        // row = lag chunk
    const int jl  = l & 15;
    const int j   = (w << 4) | jl; // state

    __shared__ __align__(16) float ua[2][SS];
    __shared__ __align__(16) float wmax[2][8];

    // runtime-resolve row_ror direction: got == (l&~15)|((l+1)&15)  <=> dst i = src (i+1)
    int got = __builtin_amdgcn_update_dpp(l, l, 0x121, 0xF, 0xF, false);
    bool dirA = (got == ((l & ~15) | ((l + 1) & 15)));

    State st;
#pragma unroll
    for (int s = 0; s < 16; ++s) {
        int mm = dirA ? ((jl + s) & 15) : ((jl - s) & 15);
        st.eAr[s].x = fexp2(A[(q * 32 + 2 * mm)     * SS + j] * LOG2E);
        st.eAr[s].y = fexp2(A[(q * 32 + 2 * mm + 1) * SS + j] * LOG2E);
    }
#pragma unroll
    for (int k = 0; k < 16; ++k) {
        st.eDe[k].x = fexp2(D[j * DMAXX + q * 32 + 2 * k]     * LOG2E);
        st.eDe[k].y = fexp2(D[j * DMAXX + q * 32 + 2 * k + 1] * LOG2E);
    }
#pragma unroll
    for (int k = 0; k < 16; ++k) {
        st.eDo[k].x = st.eDe[k].y;
        st.eDo[k].y = st.eDe[(k + 1) & 15].x;
    }
#pragma unroll
    for (int k = 0; k < 16; ++k) { st.rp[k].x = 0.f; st.rp[k].y = 0.f; }
    st.eD0  = fexp2(D[j * DMAXX] * LOG2E);
    st.C    = 0.f;
    st.e_pi = fexp2(pi[j] * LOG2E);

    const float* __restrict__ lb = logB + ((size_t)b * TT) * SS + j;
#pragma unroll
    for (int k = 0; k < 4; ++k) st.pf[k] = lb[(size_t)k * SS];

    Ctx c;
    c.up0  = (const f2*)&ua[0][0] + l;     // lane l reads U[2l..2l+1] (chunk q, pair jl)
    c.up1  = (const f2*)&ua[1][0] + l;
    c.wm0  = &wmax[0][l & 7];
    c.wm1  = &wmax[1][l & 7];
    c.wlt16 = (l < 16);
    c.wact  = (l <= 16);
    c.row0  = (q == 0);
    c.w0p  = c.wlt16 ? &ua[0][j] : (l == 16 ? &wmax[0][w] : &ua[0][0]);
    c.w1p  = c.wlt16 ? &ua[1][j] : (l == 16 ? &wmax[1][w] : &ua[1][0]);
    c.ax16 = ((l ^ 16) & 63) << 2;
    c.ax32 = ((l ^ 32) & 63) << 2;
    c.acar = ((l + 48) & 63) << 2;         // pull from lane l-16 (row q-1, same jl)
    c.lb   = lb;

    // t=0 reads wmax[1]: identity normalizer
    if (tid < 8) wmax[1][tid] = 1.0f;
    __syncthreads();

    for (int tb = 0; tb < TT; tb += 32) {
        hsmm_step< 0>(st, c, tb); hsmm_step< 1>(st, c, tb);
        hsmm_step< 2>(st, c, tb); hsmm_step< 3>(st, c, tb);
        hsmm_step< 4>(st, c, tb); hsmm_step< 5>(st, c, tb);
        hsmm_step< 6>(st, c, tb); hsmm_step< 7>(st, c, tb);
        hsmm_step< 8>(st, c, tb); hsmm_step< 9>(st, c, tb);
        hsmm_step<10>(st, c, tb); hsmm_step<11>(st, c, tb);
        hsmm_step<12>(st, c, tb); hsmm_step<13>(st, c, tb);
        hsmm_step<14>(st, c, tb); hsmm_step<15>(st, c, tb);
        hsmm_step<16>(st, c, tb); hsmm_step<17>(st, c, tb);
        hsmm_step<18>(st, c, tb); hsmm_step<19>(st, c, tb);
        hsmm_step<20>(st, c, tb); hsmm_step<21>(st, c, tb);
        hsmm_step<22>(st, c, tb); hsmm_step<23>(st, c, tb);
        hsmm_step<24>(st, c, tb); hsmm_step<25>(st, c, tb);
        hsmm_step<26>(st, c, tb); hsmm_step<27>(st, c, tb);
        hsmm_step<28>(st, c, tb); hsmm_step<29>(st, c, tb);
        hsmm_step<30>(st, c, tb); hsmm_step<31>(st, c, tb);
    }

    // epilogue: out[b] = C + log(sum_j U_{T-1}[j]);  (T-1)&1 == 1
    if (tid == 0) {
        float s = 0.f;
        for (int i = 0; i < SS; ++i) s += ua[1][i];
        out[b] = st.C + flog2(s) * LN2;
    }
}

extern "C" void kernel_launch(void* const* d_in, const int* in_sizes, int n_in,
                              void* d_out, int out_size, void* d_ws, size_t ws_size,
                              hipStream_t stream) {
    const float* logB = (const float*)d_in[0];   // (64, 2048, 128) f32
    const float* pi   = (const float*)d_in[1];   // (128,) f32
    const float* A    = (const float*)d_in[2];   // (128, 128) f32
    const float* D    = (const float*)d_in[3];   // (128, 128) f32
    float* out        = (float*)d_out;           // (64,) f32
    hipLaunchKernelGGL(hsmm_fwd_kernel, dim3(NBATCH), dim3(512), 0, stream,
                       logB, pi, A, D, out);
}

// Round 6
// 1377.413 us; speedup vs baseline: 1.2011x; 1.2011x over previous
//
#include <hip/hip_runtime.h>

#define TT 2048
#define SS 128
#define DMAXX 128
#define NBATCH 64

typedef float f2 __attribute__((ext_vector_type(2)));

__device__ __forceinline__ float fexp2(float x){ return __builtin_amdgcn_exp2f(x); }
__device__ __forceinline__ float flog2(float x){ return __builtin_amdgcn_logf(x); }
__device__ __forceinline__ float frcp (float x){ return __builtin_amdgcn_rcpf(x); }

__device__ __forceinline__ f2 pk_mul(f2 a, f2 b){
    f2 d; asm("v_pk_mul_f32 %0, %1, %2" : "=v"(d) : "v"(a), "v"(b)); return d;
}
__device__ __forceinline__ f2 pk_fma(f2 a, f2 b, f2 c){
    f2 d; asm("v_pk_fma_f32 %0, %1, %2, %3" : "=v"(d) : "v"(a), "v"(b), "v"(c)); return d;
}

template<int CTRL>
__device__ __forceinline__ float dppf(float x) {
    int i = __float_as_int(x);
    return __int_as_float(__builtin_amdgcn_update_dpp(i, i, CTRL, 0xF, 0xF, false));
}
__device__ __forceinline__ f2 ror4(f2 u) {   // row_ror:4 on both halves
    f2 v; v.x = dppf<0x124>(u.x); v.y = dppf<0x124>(u.y); return v;
}
#define DPP_XOR1   0xB1  // quad_perm(1,0,3,2)
#define DPP_XOR2   0x4E  // quad_perm(2,3,0,1)
#define DPP_SHUP1  0x90  // quad_perm(0,0,1,2)
#define DPP_ROR4   0x124
#define DPP_ROR8   0x128
#define DPP_BC15   0x142
#define DPP_BC31   0x143

constexpr float LOG2E = 1.4426950408889634f;
constexpr float LN2   = 0.6931471805599453f;

struct State {
    f2    rp[16];   // ring, register-renamed: reg rho=31-PHI receives the fresh slot
    f2    eAh[16];  // hop-ordered eA pairs: eAh[4k+p] for hop k (direction-resolved)
    float eD[32];   // eD[k] = exp(D[j][32q+k]) — scalar, no pairing constraints
    float eD0;      // exp(D[j][0]) — weight of the fresh lag-1 slot (q==0 patch)
    float pf[4];    // logB prefetch, distance 4
    float C;
    float e_pi;
};

struct Ctx {
    const float4* up0; const float4* up1;  // 2×b128 U read (4-way broadcast)
    const f2*     wm0; const f2*     wm1;  // b64 wmax read (quad covers all 8)
    float* uaw0; float* uaw1;              // ua write ptr (q==0 lanes)
    f2*    wmw0; f2*    wmw1;              // wmax write ptr (lane63), pair write
    bool q0, l63;
    const float* lb;
};

template<int PHI>
__device__ __forceinline__ void hsmm_step(State& st, const Ctx& c, int tb)
{
    constexpr int rho = 31 - PHI;        // reg receiving the fresh (lag-1) slot
    constexpr int pb  = (PHI + 1) & 1;
    constexpr int wb  = PHI & 1;
    const int t = tb + PHI;

    // ---- issue LDS reads first ----
    f2 wv = (pb ? c.wm1 : c.wm0)[0];               // 2 of the 8 wave-maxes
    const float4* up = pb ? c.up1 : c.up0;
    float4 ua0 = up[0];
    float4 ua1 = up[1];
    float rold;                                    // expiring slot (pre-scale)
    if constexpr (rho & 1) rold = st.rp[rho >> 1].y; else rold = st.rp[rho >> 1].x;
    float car = dppf<DPP_SHUP1>(rold);             // quad: lane q gets q-1's expiring

    // ---- normalizer m = max of 8 (pair-max + quad xor reduce) ----
    float m = fmaxf(wv.x, wv.y);
    m = fmaxf(m, dppf<DPP_XOR1>(m));
    m = fmaxf(m, dppf<DPP_XOR2>(m));
    st.C += flog2(m) * LN2;
    float inv_m = frcp(m);

    // ---- emission multiplier; keep prefetch 4 ahead ----
    float xB = st.pf[PHI & 3];                     // logB[t]
    if (t + 4 < TT) st.pf[PHI & 3] = c.lb[(size_t)(t + 4) * SS];
    float g = fexp2(xB * LOG2E) * inv_m;

    // ---- trans: own 8 floats + 3 row_ror:4 hops circulate the row's 32-chunk ----
    f2 u0; u0.x = ua0.x; u0.y = ua0.y;
    f2 u1; u1.x = ua0.z; u1.y = ua0.w;
    f2 u2; u2.x = ua1.x; u2.y = ua1.y;
    f2 u3; u3.x = ua1.z; u3.y = ua1.w;
    f2 a0 = pk_mul(u0, st.eAh[0]);
    f2 a1 = pk_mul(u1, st.eAh[1]);
    f2 a2 = pk_mul(u2, st.eAh[2]);
    f2 a3 = pk_mul(u3, st.eAh[3]);
#pragma unroll
    for (int k = 1; k < 4; ++k) {
        u0 = ror4(u0); u1 = ror4(u1); u2 = ror4(u2); u3 = ror4(u3);
        a0 = pk_fma(u0, st.eAh[4 * k + 0], a0);
        a1 = pk_fma(u1, st.eAh[4 * k + 1], a1);
        a2 = pk_fma(u2, st.eAh[4 * k + 2], a2);
        a3 = pk_fma(u3, st.eAh[4 * k + 3], a3);
    }
    f2 asum = (a0 + a1) + (a2 + a3);
    float tp = asum.x + asum.y;                    // chunk-q partial
    tp += dppf<DPP_XOR1>(tp);
    tp += dppf<DPP_XOR2>(tp);                      // full Etrans[j], quad-uniform
    if constexpr (PHI == 0) { if (tb == 0) tp = st.e_pi; }

    // ---- ring scale + insert (q==0 inserts 0 now, patched with tp*g after dur) ----
    float insg = (c.q0 ? 0.f : car) * g;
    f2 gg; gg.x = g; gg.y = g;
#pragma unroll
    for (int m2 = 0; m2 < 16; ++m2) st.rp[m2] = pk_mul(st.rp[m2], gg);
    if constexpr (rho & 1) st.rp[rho >> 1].y = insg;
    else                   st.rp[rho >> 1].x = insg;

    // ---- duration sum: scalar FMAs, rotating weight eD[(s+PHI+1)&31] ----
    float d0 = 0.f, d1 = 0.f, d2 = 0.f, d3 = 0.f;
#pragma unroll
    for (int m2 = 0; m2 < 16; ++m2) {
        d0 = fmaf(st.rp[m2].x, st.eD[(2 * m2 + PHI + 1) & 31], d0);
        d1 = fmaf(st.rp[m2].y, st.eD[(2 * m2 + PHI + 2) & 31], d1);
    }
    float ds = (d0 + d1) + (d2 + d3);
    ds += dppf<DPP_XOR1>(ds);
    ds += dppf<DPP_XOR2>(ds);                      // lags 2..128 (+q>0 lag chains)

    float tpg = tp * g;
    float U = fmaf(tpg, st.eD0, ds);               // + lag-1 contribution
    if (c.q0) {                                    // patch the real fresh slot
        if constexpr (rho & 1) st.rp[rho >> 1].y = tpg;
        else                   st.rp[rho >> 1].x = tpg;
    }

    // ---- wave max (R4's verified chain, lane63 holds result) ----
    float wm = U;
    wm = fmaxf(wm, dppf<DPP_ROR4>(wm));
    wm = fmaxf(wm, dppf<DPP_ROR8>(wm));
    wm = fmaxf(wm, dppf<DPP_BC15>(wm));
    wm = fmaxf(wm, dppf<DPP_BC31>(wm));

    // ---- writes ----
    if (c.q0) *(wb ? c.uaw1 : c.uaw0) = U;
    if (c.l63) { f2 wmp; wmp.x = wm; wmp.y = wm; *(wb ? c.wmw1 : c.wmw0) = wmp; }

    asm volatile("s_waitcnt lgkmcnt(0)\n\ts_barrier" ::: "memory");
}

__launch_bounds__(512, 2)
__global__ void hsmm_fwd_kernel(const float* __restrict__ logB,
                                const float* __restrict__ pi,
                                const float* __restrict__ A,
                                const float* __restrict__ D,
                                float* __restrict__ out)
{
    const int b   = blockIdx.x;
    const int tid = threadIdx.x;
    const int l   = tid & 63;
    const int w   = tid >> 6;
    const int j   = tid >> 2;      // state (j = 16w + (l>>2))
    const int q   = tid & 3;       // lag chunk
    const int jr  = (l >> 2) & 3;  // position within 16-lane row

    // wmax stored as 8 pairs (duplicated) so the read is one b64 per lane.
    __shared__ __align__(16) float ua[2][SS];
    __shared__ __align__(16) f2 wmax[2][8];   // [.][2w' and w'] duplicated pair

    // runtime-resolve row_ror:4 direction (R5-verified probe method)
    int got4 = __builtin_amdgcn_update_dpp(l, l, 0x124, 0xF, 0xF, false);
    bool dirA = (got4 == ((l & ~15) | ((l + 4) & 15)));

    State st;
#pragma unroll
    for (int k = 0; k < 4; ++k) {
        int bk = dirA ? ((jr + k) & 3) : ((jr - k) & 3);   // block held at hop k
#pragma unroll
        for (int p = 0; p < 4; ++p) {
            int i = 32 * q + 8 * bk + 2 * p;
            st.eAh[4 * k + p].x = fexp2(A[(i)     * SS + j] * LOG2E);
            st.eAh[4 * k + p].y = fexp2(A[(i + 1) * SS + j] * LOG2E);
        }
    }
#pragma unroll
    for (int k = 0; k < 32; ++k)
        st.eD[k] = fexp2(D[j * DMAXX + 32 * q + k] * LOG2E);
#pragma unroll
    for (int k = 0; k < 16; ++k) { st.rp[k].x = 0.f; st.rp[k].y = 0.f; }
    st.eD0  = fexp2(D[j * DMAXX] * LOG2E);
    st.C    = 0.f;
    st.e_pi = fexp2(pi[j] * LOG2E);

    const float* __restrict__ lb = logB + ((size_t)b * TT) * SS + j;
#pragma unroll
    for (int k = 0; k < 4; ++k) st.pf[k] = lb[(size_t)k * SS];

    Ctx c;
    c.up0  = (const float4*)&ua[0][32 * q + 8 * jr];
    c.up1  = (const float4*)&ua[1][32 * q + 8 * jr];
    c.wm0  = &wmax[0][2 * q];      // quad lanes read pairs 0,2,4,6 -> all 8 values
    c.wm1  = &wmax[1][2 * q];
    c.q0   = (q == 0);
    c.l63  = (l == 63);
    c.uaw0 = &ua[0][j];
    c.uaw1 = &ua[1][j];
    c.wmw0 = &wmax[0][w];          // lane63 writes its wave's duplicated pair
    c.wmw1 = &wmax[1][w];
    c.lb   = lb;

    // t=0 reads wmax[1]: identity normalizer
    if (tid < 8) { wmax[1][tid].x = 1.0f; wmax[1][tid].y = 1.0f; }
    __syncthreads();

    for (int tb = 0; tb < TT; tb += 32) {
        hsmm_step< 0>(st, c, tb); hsmm_step< 1>(st, c, tb);
        hsmm_step< 2>(st, c, tb); hsmm_step< 3>(st, c, tb);
        hsmm_step< 4>(st, c, tb); hsmm_step< 5>(st, c, tb);
        hsmm_step< 6>(st, c, tb); hsmm_step< 7>(st, c, tb);
        hsmm_step< 8>(st, c, tb); hsmm_step< 9>(st, c, tb);
        hsmm_step<10>(st, c, tb); hsmm_step<11>(st, c, tb);
        hsmm_step<12>(st, c, tb); hsmm_step<13>(st, c, tb);
        hsmm_step<14>(st, c, tb); hsmm_step<15>(st, c, tb);
        hsmm_step<16>(st, c, tb); hsmm_step<17>(st, c, tb);
        hsmm_step<18>(st, c, tb); hsmm_step<19>(st, c, tb);
        hsmm_step<20>(st, c, tb); hsmm_step<21>(st, c, tb);
        hsmm_step<22>(st, c, tb); hsmm_step<23>(st, c, tb);
        hsmm_step<24>(st, c, tb); hsmm_step<25>(st, c, tb);
        hsmm_step<26>(st, c, tb); hsmm_step<27>(st, c, tb);
        hsmm_step<28>(st, c, tb); hsmm_step<29>(st, c, tb);
        hsmm_step<30>(st, c, tb); hsmm_step<31>(st, c, tb);
    }

    // epilogue: out[b] = C + log(sum_j U_{T-1}[j]);  (T-1)&1 == 1
    if (tid == 0) {
        float s = 0.f;
        for (int i = 0; i < SS; ++i) s += ua[1][i];
        out[b] = st.C + flog2(s) * LN2;
    }
}

extern "C" void kernel_launch(void* const* d_in, const int* in_sizes, int n_in,
                              void* d_out, int out_size, void* d_ws, size_t ws_size,
                              hipStream_t stream) {
    const float* logB = (const float*)d_in[0];   // (64, 2048, 128) f32
    const float* pi   = (const float*)d_in[1];   // (128,) f32
    const float* A    = (const float*)d_in[2];   // (128, 128) f32
    const float* D    = (const float*)d_in[3];   // (128, 128) f32
    float* out        = (float*)d_out;           // (64,) f32
    hipLaunchKernelGGL(hsmm_fwd_kernel, dim3(NBATCH), dim3(512), 0, stream,
                       logB, pi, A, D, out);
}

// Round 7
// 1027.758 us; speedup vs baseline: 1.6097x; 1.3402x over previous
//
#include <hip/hip_runtime.h>

#define TT 2048
#define SS 128
#define DMAXX 128
#define NBATCH 64

typedef float f2 __attribute__((ext_vector_type(2)));

__device__ __forceinline__ float fexp2(float x){ return __builtin_amdgcn_exp2f(x); }
__device__ __forceinline__ float flog2(float x){ return __builtin_amdgcn_logf(x); }
__device__ __forceinline__ float frcp (float x){ return __builtin_amdgcn_rcpf(x); }

__device__ __forceinline__ f2 pk_mul(f2 a, f2 b){
    f2 d; asm("v_pk_mul_f32 %0, %1, %2" : "=v"(d) : "v"(a), "v"(b)); return d;
}
__device__ __forceinline__ f2 pk_fma(f2 a, f2 b, f2 c){
    f2 d; asm("v_pk_fma_f32 %0, %1, %2, %3" : "=v"(d) : "v"(a), "v"(b), "v"(c)); return d;
}

template<int CTRL>
__device__ __forceinline__ float dppf(float x) {
    int i = __float_as_int(x);
    return __int_as_float(__builtin_amdgcn_update_dpp(i, i, CTRL, 0xF, 0xF, false));
}
#define DPP_XOR1   0xB1  // quad_perm(1,0,3,2)
#define DPP_XOR2   0x4E  // quad_perm(2,3,0,1)
#define DPP_SHUP1  0x90  // quad_perm(0,0,1,2)
#define DPP_ROR4   0x124
#define DPP_ROR8   0x128
#define DPP_BC15   0x142
#define DPP_BC31   0x143

constexpr float LOG2E = 1.4426950408889634f;
constexpr float LN2   = 0.6931471805599453f;

// Layout (R4, measured 0 bank conflicts): j = tid>>2 (state), q = tid&3 (lag chunk).
// Thread (j,q) owns ring lags [32q+1..32q+32] (register-renamed), eA[32q..][j], eD[j][32q..].
// Scaled forward in exp domain. Renormalization every 8 steps (exact — any positive
// scalar; C2 absorbs log2 m). 1-step-stale feedback applied sparsely (stable; the
// 2-step-stale per-step variant was the R2 NaN).
struct State {
    f2    rp[16];   // ring: at end of step t, slot s (s=2m2+{0,1}) holds lag pos (s+t+1)&31
    f2    eAp[16];  // (eA[2k], eA[2k+1]), eA[i]=exp(A[32q+i][j])
    float eD[32];   // exp(D[j][32q+k])
    float eD0;      // exp(D[j][0]) — lag-1 weight for the fresh slot
    float pf[4];    // logB prefetch, distance 4
    float C2;       // accumulated log2(m)
    float e_pi;
};

struct Ctx {
    const float4* up0; const float4* up1;  // ua chunk reads (broadcast, stride-36 chunks)
    const f2*     wmp;                     // renorm read: pair (wm[2q], wm[2q+1])
    float* uaw0; float* uaw1;              // U write (q==0 lanes)
    float* wmwp;                           // wave-max write (lane 63)
    bool q0, l63;
    const float* lb;
};

template<int PHI>
__device__ __forceinline__ void hsmm_step(State& st, const Ctx& c, int tb)
{
    constexpr int  rho   = 31 - PHI;          // slot receiving the fresh (lag-1) datum
    constexpr int  pb    = (PHI + 1) & 1;
    constexpr int  wb    = PHI & 1;
    constexpr bool DO_WM = ((PHI & 7) == 6);  // compute+write wave maxes
    constexpr bool DO_RN = ((PHI & 7) == 7);  // renormalize by max of step PHI-1
    const int t = tb + PHI;

    // ---- issue all ua loads up front (8 x b128, broadcast, conflict-free) ----
    const float4* up = pb ? c.up1 : c.up0;
    float4 v[8];
#pragma unroll
    for (int k = 0; k < 8; ++k) v[k] = up[k];

    // ---- step multiplier g (no LDS on 7/8 steps) ----
    float xB = st.pf[PHI & 3];                 // logB[t]
    if (t + 4 < TT) st.pf[PHI & 3] = c.lb[(size_t)(t + 4) * SS];
    float g = fexp2(xB * LOG2E);
    if constexpr (DO_RN) {
        f2 wv = *c.wmp;                        // 2 of 8 wave maxes (written at PHI-1)
        float m = fmaxf(wv.x, wv.y);
        m = fmaxf(m, dppf<DPP_XOR1>(m));
        m = fmaxf(m, dppf<DPP_XOR2>(m));       // max over all 8 waves
        st.C2 += flog2(m);
        g *= frcp(m);
    }

    // ---- ring: carry expiring slot (independent of tp), scale, insert ----
    float rold;
    if constexpr (rho & 1) rold = st.rp[rho >> 1].y; else rold = st.rp[rho >> 1].x;
    float car  = dppf<DPP_SHUP1>(rold);        // lag-neighbor's expiring slot (same j)
    float insg = (c.q0 ? 0.f : car) * g;       // q0 inserts 0 now, patched with tp*g later
    f2 gg; gg.x = g; gg.y = g;
#pragma unroll
    for (int m2 = 0; m2 < 16; ++m2) st.rp[m2] = pk_mul(st.rp[m2], gg);
    if constexpr (rho & 1) st.rp[rho >> 1].y = insg;
    else                   st.rp[rho >> 1].x = insg;

    // ---- duration sum (R6-verified rotating index), 4 accumulators ----
    float d0 = 0.f, d1 = 0.f, d2 = 0.f, d3 = 0.f;
#pragma unroll
    for (int m2 = 0; m2 < 16; m2 += 2) {
        d0 = fmaf(st.rp[m2].x,     st.eD[(2 * m2 + PHI + 1) & 31], d0);
        d1 = fmaf(st.rp[m2].y,     st.eD[(2 * m2 + PHI + 2) & 31], d1);
        d2 = fmaf(st.rp[m2 + 1].x, st.eD[(2 * m2 + PHI + 3) & 31], d2);
        d3 = fmaf(st.rp[m2 + 1].y, st.eD[(2 * m2 + PHI + 4) & 31], d3);
    }
    float ds = (d0 + d1) + (d2 + d3);
    ds += dppf<DPP_XOR1>(ds);
    ds += dppf<DPP_XOR2>(ds);                  // lags 2..128 (quad-uniform)

    // ---- trans: Etrans[j] = sum_i U_prev[i]*eA[i][j] over chunk q, then quad-reduce ----
    f2 a0, a1, a2, a3;
    {
        f2 u;
        u.x = v[0].x; u.y = v[0].y; a0 = pk_mul(u, st.eAp[0]);
        u.x = v[0].z; u.y = v[0].w; a1 = pk_mul(u, st.eAp[1]);
        u.x = v[1].x; u.y = v[1].y; a2 = pk_mul(u, st.eAp[2]);
        u.x = v[1].z; u.y = v[1].w; a3 = pk_mul(u, st.eAp[3]);
#pragma unroll
        for (int kk = 2; kk < 8; kk += 2) {
            u.x = v[kk].x;     u.y = v[kk].y;     a0 = pk_fma(u, st.eAp[2 * kk],     a0);
            u.x = v[kk].z;     u.y = v[kk].w;     a1 = pk_fma(u, st.eAp[2 * kk + 1], a1);
            u.x = v[kk + 1].x; u.y = v[kk + 1].y; a2 = pk_fma(u, st.eAp[2 * kk + 2], a2);
            u.x = v[kk + 1].z; u.y = v[kk + 1].w; a3 = pk_fma(u, st.eAp[2 * kk + 3], a3);
        }
    }
    f2 asum = (a0 + a1) + (a2 + a3);
    float tp = asum.x + asum.y;
    tp += dppf<DPP_XOR1>(tp);
    tp += dppf<DPP_XOR2>(tp);                  // full Etrans[j], quad-uniform
    if constexpr (PHI == 0) { if (tb == 0) tp = st.e_pi; }   // t==0: entry = pi

    // ---- join: U = dur(lags>=2) + fresh lag-1 term; patch the real fresh slot ----
    float tpg = tp * g;
    float U = fmaf(tpg, st.eD0, ds);
    if (c.q0) {
        if constexpr (rho & 1) st.rp[rho >> 1].y = tpg;
        else                   st.rp[rho >> 1].x = tpg;
    }
    if (c.q0) *(wb ? c.uaw1 : c.uaw0) = U;

    // ---- wave max only on pre-renorm steps ----
    if constexpr (DO_WM) {
        float wm = U;
        wm = fmaxf(wm, dppf<DPP_ROR4>(wm));
        wm = fmaxf(wm, dppf<DPP_ROR8>(wm));
        wm = fmaxf(wm, dppf<DPP_BC15>(wm));
        wm = fmaxf(wm, dppf<DPP_BC31>(wm));    // lane63 = max over wave's 16 states
        if (c.l63) *c.wmwp = wm;
    }

    asm volatile("s_waitcnt lgkmcnt(0)\n\ts_barrier" ::: "memory");
}

__launch_bounds__(512, 2)
__global__ void hsmm_fwd_kernel(const float* __restrict__ logB,
                                const float* __restrict__ pi,
                                const float* __restrict__ A,
                                const float* __restrict__ D,
                                float* __restrict__ out)
{
    const int b   = blockIdx.x;
    const int tid = threadIdx.x;
    const int l   = tid & 63;
    const int w   = tid >> 6;
    const int j   = tid >> 2;
    const int q   = tid & 3;

    // chunk c at c*36 floats: 16B-aligned, bank-spread (R4: 0 conflicts)
    __shared__ __align__(16) float ua[2][4 * 36];
    __shared__ __align__(16) float wmaxf[8];

    State st;
#pragma unroll
    for (int k = 0; k < 16; ++k) {
        st.eAp[k].x = fexp2(A[(q * 32 + 2 * k)     * SS + j] * LOG2E);
        st.eAp[k].y = fexp2(A[(q * 32 + 2 * k + 1) * SS + j] * LOG2E);
    }
#pragma unroll
    for (int k = 0; k < 32; ++k)
        st.eD[k] = fexp2(D[j * DMAXX + q * 32 + k] * LOG2E);
#pragma unroll
    for (int k = 0; k < 16; ++k) { st.rp[k].x = 0.f; st.rp[k].y = 0.f; }
    st.eD0  = fexp2(D[j * DMAXX] * LOG2E);
    st.C2   = 0.f;
    st.e_pi = fexp2(pi[j] * LOG2E);

    const float* __restrict__ lb = logB + ((size_t)b * TT) * SS + j;
#pragma unroll
    for (int k = 0; k < 4; ++k) st.pf[k] = lb[(size_t)k * SS];

    Ctx c;
    c.up0  = (const float4*)&ua[0][q * 36];
    c.up1  = (const float4*)&ua[1][q * 36];
    c.wmp  = (const f2*)&wmaxf[2 * q];     // quad covers all 8 wave maxes
    c.q0   = (q == 0);
    c.l63  = (l == 63);
    c.uaw0 = &ua[0][(j >> 5) * 36 + (j & 31)];
    c.uaw1 = &ua[1][(j >> 5) * 36 + (j & 31)];
    c.wmwp = &wmaxf[w];
    c.lb   = lb;

    // no LDS init needed: t=0 trans result is overridden by e_pi; first renorm
    // (t=7) reads wmaxf written at t=6.

    for (int tb = 0; tb < TT; tb += 32) {
        hsmm_step< 0>(st, c, tb); hsmm_step< 1>(st, c, tb);
        hsmm_step< 2>(st, c, tb); hsmm_step< 3>(st, c, tb);
        hsmm_step< 4>(st, c, tb); hsmm_step< 5>(st, c, tb);
        hsmm_step< 6>(st, c, tb); hsmm_step< 7>(st, c, tb);
        hsmm_step< 8>(st, c, tb); hsmm_step< 9>(st, c, tb);
        hsmm_step<10>(st, c, tb); hsmm_step<11>(st, c, tb);
        hsmm_step<12>(st, c, tb); hsmm_step<13>(st, c, tb);
        hsmm_step<14>(st, c, tb); hsmm_step<15>(st, c, tb);
        hsmm_step<16>(st, c, tb); hsmm_step<17>(st, c, tb);
        hsmm_step<18>(st, c, tb); hsmm_step<19>(st, c, tb);
        hsmm_step<20>(st, c, tb); hsmm_step<21>(st, c, tb);
        hsmm_step<22>(st, c, tb); hsmm_step<23>(st, c, tb);
        hsmm_step<24>(st, c, tb); hsmm_step<25>(st, c, tb);
        hsmm_step<26>(st, c, tb); hsmm_step<27>(st, c, tb);
        hsmm_step<28>(st, c, tb); hsmm_step<29>(st, c, tb);
        hsmm_step<30>(st, c, tb); hsmm_step<31>(st, c, tb);
    }

    // epilogue: out[b] = (C2 + log2(sum_j U_{T-1}[j])) * ln2 ;  (T-1)&1 == 1
    if (tid == 0) {
        float s = 0.f;
        for (int i = 0; i < SS; ++i) s += ua[1][(i >> 5) * 36 + (i & 31)];
        out[b] = (st.C2 + flog2(s)) * LN2;
    }
}

extern "C" void kernel_launch(void* const* d_in, const int* in_sizes, int n_in,
                              void* d_out, int out_size, void* d_ws, size_t ws_size,
                              hipStream_t stream) {
    const float* logB = (const float*)d_in[0];   // (64, 2048, 128) f32
    const float* pi   = (const float*)d_in[1];   // (128,) f32
    const float* A    = (const float*)d_in[2];   // (128, 128) f32
    const float* D    = (const float*)d_in[3];   // (128, 128) f32
    float* out        = (float*)d_out;           // (64,) f32
    hipLaunchKernelGGL(hsmm_fwd_kernel, dim3(NBATCH), dim3(512), 0, stream,
                       logB, pi, A, D, out);
}

// Round 8
// 983.455 us; speedup vs baseline: 1.6822x; 1.0450x over previous
//
#include <hip/hip_runtime.h>

#define TT 2048
#define SS 128
#define DMAXX 128
#define NBATCH 64

typedef float f2 __attribute__((ext_vector_type(2)));

__device__ __forceinline__ float fexp2(float x){ return __builtin_amdgcn_exp2f(x); }
__device__ __forceinline__ float flog2(float x){ return __builtin_amdgcn_logf(x); }
__device__ __forceinline__ float frcp (float x){ return __builtin_amdgcn_rcpf(x); }
__device__ __forceinline__ f2 pkfma(f2 a, f2 b, f2 c){ return __builtin_elementwise_fma(a, b, c); }

template<int CTRL>
__device__ __forceinline__ float dppf(float x) {
    int i = __float_as_int(x);
    return __int_as_float(__builtin_amdgcn_update_dpp(i, i, CTRL, 0xF, 0xF, false));
}
#define DPP_XOR1   0xB1  // quad_perm(1,0,3,2)
#define DPP_XOR2   0x4E  // quad_perm(2,3,0,1)
#define DPP_SHUP1  0x90  // quad_perm(0,0,1,2)
#define DPP_ROR4   0x124
#define DPP_ROR8   0x128
#define DPP_BC15   0x142
#define DPP_BC31   0x143

constexpr float LOG2E = 1.4426950408889634f;
constexpr float LN2   = 0.6931471805599453f;

// Layout (R4/R7, 0 bank conflicts): j = tid>>2 (state), q = tid&3 (lag chunk).
// Thread (j,q) owns ring lags [32q+1..32q+32] (register-renamed), eA[32q..][j], eD[j][32q..].
// Scaled forward in exp domain; renorm every 8 steps (exact — C2 absorbs log2 m).
struct State {
    f2    rp[16];   // ring: at end of step t, slot s holds lag pos (s+t+1)&31
    f2    eAp[16];  // (eA[2k], eA[2k+1]), eA[i]=exp(A[32q+i][j])
    f2    eDp[32];  // pair table: eDp[w] = (eD[w], eD[(w+1)&31]), eD[k]=exp(D[j][32q+k])
    float eD0;      // exp(D[j][0]) — lag-1 weight for the fresh slot
    float pf[4];    // logB prefetch, distance 4
    const float* pfp;  // prefetch pointer (lb + (t+4)*SS), advanced SS/step
    float C2;       // accumulated log2(m)
    float e_pi;
};

struct Ctx {
    const float4* up0; const float4* up1;  // ua chunk reads (broadcast, stride-36 chunks)
    const f2*     wmp;                     // renorm read: pair (wm[2q], wm[2q+1])
    float* uaw0; float* uaw1;              // U write (q==0 lanes)
    float* wmwp;                           // wave-max write (lane 63)
    bool q0, l63;
};

template<int PHI>
__device__ __forceinline__ void hsmm_step(State& st, const Ctx& c, int tb)
{
    constexpr int  rho   = 31 - PHI;          // slot receiving the fresh (lag-1) datum
    constexpr int  pb    = (PHI + 1) & 1;
    constexpr int  wb    = PHI & 1;
    constexpr bool DO_WM = ((PHI & 7) == 6);
    constexpr bool DO_RN = ((PHI & 7) == 7);
    const int t = tb + PHI;

    // ---- issue all ua loads up front (8 x b128, broadcast, conflict-free) ----
    const float4* up = pb ? c.up1 : c.up0;
    float4 v[8];
#pragma unroll
    for (int k = 0; k < 8; ++k) v[k] = up[k];

    // ---- step multiplier g (no LDS on 7/8 steps) ----
    float xB = st.pf[PHI & 3];                 // logB[t]
    if (t + 4 < TT) st.pf[PHI & 3] = st.pfp[0];
    st.pfp += SS;
    float g = fexp2(xB * LOG2E);
    if constexpr (DO_RN) {
        f2 wv = *c.wmp;                        // 2 of 8 wave maxes (written at PHI-1)
        float m = fmaxf(wv.x, wv.y);
        m = fmaxf(m, dppf<DPP_XOR1>(m));
        m = fmaxf(m, dppf<DPP_XOR2>(m));       // max over all 8 waves
        st.C2 += flog2(m);
        g *= frcp(m);
    }

    // ---- ring: carry expiring slot (independent of tp), scale, insert ----
    float rold;
    if constexpr (rho & 1) rold = st.rp[rho >> 1].y; else rold = st.rp[rho >> 1].x;
    float car  = dppf<DPP_SHUP1>(rold);        // lag-neighbor's expiring slot (same j)
    float insg = (c.q0 ? 0.f : car) * g;       // q0 inserts 0 now, patched with tp*g later
    f2 gg = {g, g};
#pragma unroll
    for (int m2 = 0; m2 < 16; ++m2) st.rp[m2] = st.rp[m2] * gg;
    if constexpr (rho & 1) st.rp[rho >> 1].y = insg;
    else                   st.rp[rho >> 1].x = insg;

    // ---- duration sum: packed, pair table eDp[w]=(eD[w],eD[w+1]), w=(2m2+PHI+1)&31 ----
    f2 q0a = {0.f, 0.f}, q1a = {0.f, 0.f}, q2a = {0.f, 0.f}, q3a = {0.f, 0.f};
#pragma unroll
    for (int m2 = 0; m2 < 16; m2 += 4) {
        q0a = pkfma(st.rp[m2],     st.eDp[(2 * m2 + PHI + 1) & 31], q0a);
        q1a = pkfma(st.rp[m2 + 1], st.eDp[(2 * m2 + PHI + 3) & 31], q1a);
        q2a = pkfma(st.rp[m2 + 2], st.eDp[(2 * m2 + PHI + 5) & 31], q2a);
        q3a = pkfma(st.rp[m2 + 3], st.eDp[(2 * m2 + PHI + 7) & 31], q3a);
    }
    f2 qs = (q0a + q1a) + (q2a + q3a);
    float ds = qs.x + qs.y;
    ds += dppf<DPP_XOR1>(ds);
    ds += dppf<DPP_XOR2>(ds);                  // lags 2..128 (quad-uniform)

    // ---- trans: Etrans[j] = sum_i U_prev[i]*eA[i][j] over chunk q, quad-reduce ----
    f2 a0, a1, a2, a3;
    {
        f2 u;
        u = (f2){v[0].x, v[0].y}; a0 = u * st.eAp[0];
        u = (f2){v[0].z, v[0].w}; a1 = u * st.eAp[1];
        u = (f2){v[1].x, v[1].y}; a2 = u * st.eAp[2];
        u = (f2){v[1].z, v[1].w}; a3 = u * st.eAp[3];
#pragma unroll
        for (int kk = 2; kk < 8; kk += 2) {
            u = (f2){v[kk].x,     v[kk].y};     a0 = pkfma(u, st.eAp[2 * kk],     a0);
            u = (f2){v[kk].z,     v[kk].w};     a1 = pkfma(u, st.eAp[2 * kk + 1], a1);
            u = (f2){v[kk + 1].x, v[kk + 1].y}; a2 = pkfma(u, st.eAp[2 * kk + 2], a2);
            u = (f2){v[kk + 1].z, v[kk + 1].w}; a3 = pkfma(u, st.eAp[2 * kk + 3], a3);
        }
    }
    f2 asum = (a0 + a1) + (a2 + a3);
    float tp = asum.x + asum.y;
    tp += dppf<DPP_XOR1>(tp);
    tp += dppf<DPP_XOR2>(tp);                  // full Etrans[j], quad-uniform
    if constexpr (PHI == 0) { if (tb == 0) tp = st.e_pi; }   // t==0: entry = pi

    // ---- join: U = dur(lags>=2) + fresh lag-1 term; patch the real fresh slot ----
    float tpg = tp * g;
    float U = fmaf(tpg, st.eD0, ds);
    if (c.q0) {
        if constexpr (rho & 1) st.rp[rho >> 1].y = tpg;
        else                   st.rp[rho >> 1].x = tpg;
    }
    if (c.q0) *(wb ? c.uaw1 : c.uaw0) = U;

    // ---- wave max only on pre-renorm steps ----
    if constexpr (DO_WM) {
        float wm = U;
        wm = fmaxf(wm, dppf<DPP_ROR4>(wm));
        wm = fmaxf(wm, dppf<DPP_ROR8>(wm));
        wm = fmaxf(wm, dppf<DPP_BC15>(wm));
        wm = fmaxf(wm, dppf<DPP_BC31>(wm));    // lane63 = max over wave's 16 states
        if (c.l63) *c.wmwp = wm;
    }

    asm volatile("s_waitcnt lgkmcnt(0)\n\ts_barrier" ::: "memory");
}

__launch_bounds__(512, 2)
__global__ void hsmm_fwd_kernel(const float* __restrict__ logB,
                                const float* __restrict__ pi,
                                const float* __restrict__ A,
                                const float* __restrict__ D,
                                float* __restrict__ out)
{
    const int b   = blockIdx.x;
    const int tid = threadIdx.x;
    const int l   = tid & 63;
    const int w   = tid >> 6;
    const int j   = tid >> 2;
    const int q   = tid & 3;

    // chunk c at c*36 floats: 16B-aligned, bank-spread (R4/R7: 0 conflicts)
    __shared__ __align__(16) float ua[2][4 * 36];
    __shared__ __align__(16) float wmaxf[8];

    State st;
#pragma unroll
    for (int k = 0; k < 16; ++k) {
        st.eAp[k].x = fexp2(A[(q * 32 + 2 * k)     * SS + j] * LOG2E);
        st.eAp[k].y = fexp2(A[(q * 32 + 2 * k + 1) * SS + j] * LOG2E);
    }
    {
        float eD[32];
#pragma unroll
        for (int k = 0; k < 32; ++k)
            eD[k] = fexp2(D[j * DMAXX + q * 32 + k] * LOG2E);
#pragma unroll
        for (int wdx = 0; wdx < 32; ++wdx) {
            st.eDp[wdx].x = eD[wdx];
            st.eDp[wdx].y = eD[(wdx + 1) & 31];
        }
    }
#pragma unroll
    for (int k = 0; k < 16; ++k) st.rp[k] = (f2){0.f, 0.f};
    st.eD0  = fexp2(D[j * DMAXX] * LOG2E);
    st.C2   = 0.f;
    st.e_pi = fexp2(pi[j] * LOG2E);

    const float* __restrict__ lb = logB + ((size_t)b * TT) * SS + j;
#pragma unroll
    for (int k = 0; k < 4; ++k) st.pf[k] = lb[(size_t)k * SS];
    st.pfp = lb + (size_t)4 * SS;

    Ctx c;
    c.up0  = (const float4*)&ua[0][q * 36];
    c.up1  = (const float4*)&ua[1][q * 36];
    c.wmp  = (const f2*)&wmaxf[2 * q];     // quad covers all 8 wave maxes
    c.q0   = (q == 0);
    c.l63  = (l == 63);
    c.uaw0 = &ua[0][(j >> 5) * 36 + (j & 31)];
    c.uaw1 = &ua[1][(j >> 5) * 36 + (j & 31)];
    c.wmwp = &wmaxf[w];

    for (int tb = 0; tb < TT; tb += 32) {
        hsmm_step< 0>(st, c, tb); hsmm_step< 1>(st, c, tb);
        hsmm_step< 2>(st, c, tb); hsmm_step< 3>(st, c, tb);
        hsmm_step< 4>(st, c, tb); hsmm_step< 5>(st, c, tb);
        hsmm_step< 6>(st, c, tb); hsmm_step< 7>(st, c, tb);
        hsmm_step< 8>(st, c, tb); hsmm_step< 9>(st, c, tb);
        hsmm_step<10>(st, c, tb); hsmm_step<11>(st, c, tb);
        hsmm_step<12>(st, c, tb); hsmm_step<13>(st, c, tb);
        hsmm_step<14>(st, c, tb); hsmm_step<15>(st, c, tb);
        hsmm_step<16>(st, c, tb); hsmm_step<17>(st, c, tb);
        hsmm_step<18>(st, c, tb); hsmm_step<19>(st, c, tb);
        hsmm_step<20>(st, c, tb); hsmm_step<21>(st, c, tb);
        hsmm_step<22>(st, c, tb); hsmm_step<23>(st, c, tb);
        hsmm_step<24>(st, c, tb); hsmm_step<25>(st, c, tb);
        hsmm_step<26>(st, c, tb); hsmm_step<27>(st, c, tb);
        hsmm_step<28>(st, c, tb); hsmm_step<29>(st, c, tb);
        hsmm_step<30>(st, c, tb); hsmm_step<31>(st, c, tb);
    }

    // epilogue: out[b] = (C2 + log2(sum_j U_{T-1}[j])) * ln2 ;  (T-1)&1 == 1
    if (tid == 0) {
        float s = 0.f;
        for (int i = 0; i < SS; ++i) s += ua[1][(i >> 5) * 36 + (i & 31)];
        out[b] = (st.C2 + flog2(s)) * LN2;
    }
}

extern "C" void kernel_launch(void* const* d_in, const int* in_sizes, int n_in,
                              void* d_out, int out_size, void* d_ws, size_t ws_size,
                              hipStream_t stream) {
    const float* logB = (const float*)d_in[0];   // (64, 2048, 128) f32
    const float* pi   = (const float*)d_in[1];   // (128,) f32
    const float* A    = (const float*)d_in[2];   // (128, 128) f32
    const float* D    = (const float*)d_in[3];   // (128, 128) f32
    float* out        = (float*)d_out;           // (64,) f32
    hipLaunchKernelGGL(hsmm_fwd_kernel, dim3(NBATCH), dim3(512), 0, stream,
                       logB, pi, A, D, out);
}